// Round 5
// baseline (932.515 us; speedup 1.0000x reference)
//
#include <hip/hip_runtime.h>
#include <hip/hip_cooperative_groups.h>
#include <math.h>

namespace cg = cooperative_groups;

// Problem constants: N=32768 nodes, E=262144 edges, HID=64, HEADS=4
#define HIDDEN 64
#define HEADS 4
#define HC 256   // HEADS * HIDDEN
#define CAP 64   // bucket capacity per dst node (Poisson(8): P(deg>64) ~ 0)
#define GRID 1024

typedef __attribute__((ext_vector_type(8))) short short8;   // 8 bf16 (4 VGPRs)
typedef __attribute__((ext_vector_type(4))) float f32x4;    // MFMA acc

__device__ __forceinline__ unsigned short f2bf(float f) {
    unsigned int u = __float_as_uint(f);
    u += 0x7fffu + ((u >> 16) & 1u);   // round-to-nearest-even
    return (unsigned short)(u >> 16);
}
__device__ __forceinline__ unsigned short f2h(float f) {
    _Float16 h = (_Float16)f;
    return *(unsigned short*)&h;
}
__device__ __forceinline__ float h2f(unsigned int u) {
    unsigned short s = (unsigned short)u;
    _Float16 h = *(_Float16*)&s;
    return (float)h;
}
__device__ __forceinline__ float bflo(unsigned int u) { return __uint_as_float(u << 16); }
__device__ __forceinline__ float bfhi(unsigned int u) { return __uint_as_float(u & 0xffff0000u); }

struct MegaArgs {
    const int* dst; const int* src; const float* ea; const float* hin;
    const float* W1; const float* W2;
    const float* We1; const float* ae1; const float* We2; const float* ae2;
    const float* ats1; const float* atd1; const float* ats2; const float* atd2;
    const float* b1; const float* lg1; const float* lb1;
    const float* b2; const float* lg2; const float* lb2;
    int* counts; uint2* eb; ushort* zb; ushort* zb2;
    ushort* wst1; ushort* wst2; float* wsv; float* wr;
    float* as1v; float* ad1v; float* as2v; float* ad2v;
    float* outf; int N; int E;
};

// ---------------- phase 0: prep + bucket (1 edge/thread over 1024x256) ------
__device__ __forceinline__ void prep_phase(const MegaArgs& a) {
    int tid = blockIdx.x * 256 + threadIdx.x;   // 0..262143
    if (tid < a.E) {
        int d = a.dst[tid];
        int c = atomicAdd(&a.counts[d], 1);
        if (c < CAP) {
            int slot = d * CAP + c;
            unsigned lo = (unsigned)(a.src[tid] & 0xffff)
                        | ((unsigned)f2h(a.ea[tid * 3 + 0]) << 16);
            unsigned hi = (unsigned)f2h(a.ea[tid * 3 + 1])
                        | ((unsigned)f2h(a.ea[tid * 3 + 2]) << 16);
            a.eb[slot] = make_uint2(lo, hi);
        }
    }
#pragma unroll
    for (int rr = 0; rr < 2; ++rr) {            // zb: 2 float4 per thread
        int i = tid + rr * (GRID * 256);
        float4 v = ((const float4*)a.hin)[i];
        ushort4 o;
        o.x = f2bf(v.x); o.y = f2bf(v.y); o.z = f2bf(v.z); o.w = f2bf(v.w);
        ((ushort4*)a.zb)[i] = o;
    }
    if (tid < 32768) {                          // stacked transposed W (both layers)
        int j = tid;
        const float* W = (j < 16384) ? a.W1 : a.W2;
        ushort* wst = (j < 16384) ? a.wst1 : a.wst2;
        int i = j & 16383, c = i >> 8, k = i & 255;
        wst[i] = f2bf(0.25f * W[(k & 63) * HC + (k >> 6) * 64 + c]);
    }
    if (tid < 1024) {                           // wsv: W @ att_{src,dst}
        int r = tid >> 8, idx = tid & 255, hh = idx >> 6, k = idx & 63;
        const float* W = (r >> 1) ? a.W2 : a.W1;
        const float* at = (r == 0) ? a.ats1 : (r == 1) ? a.atd1
                        : (r == 2) ? a.ats2 : a.atd2;
        float v = 0.f;
        for (int c = 0; c < 64; ++c) v += W[k * HC + hh * 64 + c] * at[hh * 64 + c];
        a.wsv[r * 256 + hh * 64 + k] = v;
    }
    if (tid < 32) {                             // wr: We @ att_edge
        int layer = tid >> 4, idx = tid & 15;
        if (idx < 12) {
            int d = idx >> 2, hh = idx & 3;
            const float* We = layer ? a.We2 : a.We1;
            const float* ae = layer ? a.ae2 : a.ae1;
            float v = 0.f;
            for (int l = 0; l < 64; ++l) v += We[d * HC + hh * 64 + l] * ae[hh * 64 + l];
            a.wr[layer * 16 + d * HEADS + hh] = v;
        }
    }
}

// ---------------- alpha: as/ad = z @ ws/wd (128 blocks, 1 node/thread) ------
__device__ __forceinline__ void alpha_body(const ushort* zsrc, const float* wsv,
                                           float* asv, float* adv, float* ls) {
    int t = threadIdx.x;
    ls[t] = wsv[t];
    ls[t + 256] = wsv[t + 256];
    __syncthreads();
    int n = blockIdx.x * 256 + t;
    const ushort* zr = zsrc + (size_t)n * HIDDEN;
    float as[4] = {0.f, 0.f, 0.f, 0.f};
    float ad[4] = {0.f, 0.f, 0.f, 0.f};
#pragma unroll
    for (int ks = 0; ks < 8; ++ks) {
        uint4 v = *(const uint4*)(zr + ks * 8);
        unsigned int uu[4] = {v.x, v.y, v.z, v.w};
#pragma unroll
        for (int p = 0; p < 4; ++p) {
            float f0 = bflo(uu[p]), f1 = bfhi(uu[p]);
            int k = ks * 8 + p * 2;
#pragma unroll
            for (int hh = 0; hh < 4; ++hh) {
                as[hh] += f0 * ls[hh * 64 + k] + f1 * ls[hh * 64 + k + 1];
                ad[hh] += f0 * ls[256 + hh * 64 + k] + f1 * ls[256 + hh * 64 + k + 1];
            }
        }
    }
    *(float4*)&asv[n * 4] = make_float4(as[0], as[1], as[2], as[3]);
    *(float4*)&adv[n * 4] = make_float4(ad[0], ad[1], ad[2], ad[3]);
}

// ---------------- aggregate (4-node pipelined) + all-wave out-GEMM ----------
__device__ __forceinline__ void aggout_tile(
        int nbase, const ushort* zsrc, const uint2* eb, const int* counts,
        const float* asv, const float* adv, const float* wrl,
        const ushort* wst, const float* bias, const float* lng, const float* lnb,
        float* outf, ushort* outb,
        ushort (*sagg)[264], float (*pst)[4][2]) {
    int lane = threadIdx.x & 63;
    int wave = threadIdx.x >> 6;
    int h = lane >> 4, sub = lane & 15;

    float w0 = wrl[h], w1 = wrl[4 + h], w2 = wrl[8 + h];

    int degs[4]; float ad4s[4]; int bases[4];
#pragma unroll
    for (int i = 0; i < 4; ++i) {
        int n = nbase + wave * 4 + i;
        int d = counts[n];
        degs[i] = (d > CAP) ? CAP : d;
        ad4s[i] = adv[(size_t)n * 4 + h];
        bases[i] = n * CAP;
    }
    // A: issue 4 independent record loads (chunk 0)
    uint2 rec[4];
#pragma unroll
    for (int i = 0; i < 4; ++i) rec[i] = eb[bases[i] + sub];

    // B: 4 independent alpha chains (as_ gather + exp)
    int s_sub[4]; float wgt[4];
#pragma unroll
    for (int i = 0; i < 4; ++i) {
        int ss = (sub < degs[i]) ? (int)(rec[i].x & 0xffffu) : 0;
        s_sub[i] = ss;
        float wv = 0.f;
        if (sub < degs[i]) {
            float lg = asv[(size_t)ss * 4 + h] + ad4s[i]
                     + h2f(rec[i].x >> 16) * w0
                     + h2f(rec[i].y) * w1
                     + h2f(rec[i].y >> 16) * w2;
            lg = (lg >= 0.f) ? lg : 0.2f * lg;
            wv = __expf(lg);
        }
        wgt[i] = wv;
    }
    float ssum[4];
#pragma unroll
    for (int i = 0; i < 4; ++i) ssum[i] = wgt[i];

    float acc[4][4][4];
#pragma unroll
    for (int i = 0; i < 4; ++i)
#pragma unroll
        for (int a = 0; a < 4; ++a)
#pragma unroll
            for (int j = 0; j < 4; ++j) acc[i][a][j] = 0.f;

    // C: gathers, shared trip count over the 4 nodes (chunk 0, deg<=16)
    int mx = degs[0];
    mx = (degs[1] > mx) ? degs[1] : mx;
    mx = (degs[2] > mx) ? degs[2] : mx;
    mx = (degs[3] > mx) ? degs[3] : mx;
    if (mx > 16) mx = 16;
    for (int j4 = 0; j4 < mx; j4 += 4) {
#pragma unroll
        for (int i = 0; i < 4; ++i) {
            if (j4 < degs[i]) {
                int eidx = j4 + h;
                int s_g = __shfl(s_sub[i], eidx);
                uint2 zv = *(const uint2*)&zsrc[(size_t)s_g * HIDDEN + sub * 4];
                float z0 = bflo(zv.x), z1 = bfhi(zv.x);
                float z2v = bflo(zv.y), z3 = bfhi(zv.y);
#pragma unroll
                for (int hh = 0; hh < 4; ++hh) {
                    float wh = __shfl(wgt[i], hh * 16 + eidx);
                    acc[i][hh][0] += wh * z0;
                    acc[i][hh][1] += wh * z1;
                    acc[i][hh][2] += wh * z2v;
                    acc[i][hh][3] += wh * z3;
                }
            }
        }
    }

    // tail chunks (deg > 16, ~0.4% of nodes)
#pragma unroll 1
    for (int i = 0; i < 4; ++i) {
        for (int cs = 16; cs < degs[i]; cs += 16) {
            int idx = cs + sub;
            int st = 0; float wt = 0.f;
            uint2 rt = eb[bases[i] + ((idx < degs[i]) ? idx : (cs))];
            if (idx < degs[i]) {
                st = (int)(rt.x & 0xffffu);
                float lg = asv[(size_t)st * 4 + h] + ad4s[i]
                         + h2f(rt.x >> 16) * w0 + h2f(rt.y) * w1
                         + h2f(rt.y >> 16) * w2;
                lg = (lg >= 0.f) ? lg : 0.2f * lg;
                wt = __expf(lg);
            }
            ssum[i] += wt;
            int jb = degs[i] - cs; if (jb > 16) jb = 16;
            for (int j4 = 0; j4 < jb; j4 += 4) {
                int eidx = j4 + h;
                int s_g = __shfl(st, eidx);
                uint2 zv = *(const uint2*)&zsrc[(size_t)s_g * HIDDEN + sub * 4];
                float z0 = bflo(zv.x), z1 = bfhi(zv.x);
                float z2v = bflo(zv.y), z3 = bfhi(zv.y);
#pragma unroll
                for (int hh = 0; hh < 4; ++hh) {
                    float wh = __shfl(wt, hh * 16 + eidx);
                    acc[i][hh][0] += wh * z0;
                    acc[i][hh][1] += wh * z1;
                    acc[i][hh][2] += wh * z2v;
                    acc[i][hh][3] += wh * z3;
                }
            }
        }
    }

    // reduce + normalize + write LDS tile
#pragma unroll
    for (int i = 0; i < 4; ++i) {
        float s = ssum[i];
#pragma unroll
        for (int o = 1; o < 16; o <<= 1) s += __shfl_xor(s, o);
        float winv = 1.f / (s + 1e-16f);
#pragma unroll
        for (int a = 0; a < 4; ++a)
#pragma unroll
            for (int j = 0; j < 4; ++j) {
                acc[i][a][j] += __shfl_xor(acc[i][a][j], 16);
                acc[i][a][j] += __shfl_xor(acc[i][a][j], 32);
            }
        float sel[4];
#pragma unroll
        for (int j = 0; j < 4; ++j)
            sel[j] = (h == 0) ? acc[i][0][j] : (h == 1) ? acc[i][1][j]
                   : (h == 2) ? acc[i][2][j] : acc[i][3][j];
        uint2 pk;
        pk.x = (unsigned)f2bf(sel[0] * winv) | ((unsigned)f2bf(sel[1] * winv) << 16);
        pk.y = (unsigned)f2bf(sel[2] * winv) | ((unsigned)f2bf(sel[3] * winv) << 16);
        *(uint2*)&sagg[wave * 4 + i][h * 64 + sub * 4] = pk;
    }
    __syncthreads();

    // all-wave GEMM: wave w = column tile w
    {
        int q = sub, quad = h;
        int col = wave * 16 + q;
        float bv = bias[col], gv = lng[col], bb = lnb[col];
        short8 a[8];
#pragma unroll
        for (int ks = 0; ks < 8; ++ks)
            a[ks] = *(const short8*)&sagg[q][quad * 8 + ks * 32];
        const ushort* brow = wst + (size_t)col * HC + quad * 8;
        f32x4 c4 = {0.f, 0.f, 0.f, 0.f};
#pragma unroll
        for (int ks = 0; ks < 8; ++ks) {
            short8 bfr = *(const short8*)(brow + ks * 32);
            c4 = __builtin_amdgcn_mfma_f32_16x16x32_bf16(a[ks], bfr, c4, 0, 0, 0);
        }
        float u[4], s1[4], ssq[4];
#pragma unroll
        for (int r = 0; r < 4; ++r) {
            u[r] = c4[r] + bv;
            s1[r] = u[r];
            ssq[r] = u[r] * u[r];
        }
#pragma unroll
        for (int o = 1; o < 16; o <<= 1)
#pragma unroll
            for (int r = 0; r < 4; ++r) {
                s1[r] += __shfl_xor(s1[r], o);
                ssq[r] += __shfl_xor(ssq[r], o);
            }
        if (q == 0) {
#pragma unroll
            for (int r = 0; r < 4; ++r) {
                pst[quad * 4 + r][wave][0] = s1[r];
                pst[quad * 4 + r][wave][1] = ssq[r];
            }
        }
        __syncthreads();
#pragma unroll
        for (int r = 0; r < 4; ++r) {
            int row = quad * 4 + r;
            float t1 = pst[row][0][0] + pst[row][1][0] + pst[row][2][0] + pst[row][3][0];
            float t2 = pst[row][0][1] + pst[row][1][1] + pst[row][2][1] + pst[row][3][1];
            float mu = t1 * (1.f / 64.f);
            float var = t2 * (1.f / 64.f) - mu * mu;
            float rstd = rsqrtf(var + 1e-5f);
            float y = (u[r] - mu) * rstd * gv + bb;
            float rv = y / (1.f + __expf(-y));
            if (outb) outb[(size_t)(nbase + row) * HIDDEN + col] = f2bf(rv);
            else      outf[(size_t)(nbase + row) * HIDDEN + col] = rv;
        }
    }
    __syncthreads();   // protect sagg/pst reuse by next tile
}

// ---------------- mega cooperative kernel ----------------
__global__ __launch_bounds__(256, 4) void k_mega(MegaArgs a) {
    __shared__ ushort sagg[16][264];
    __shared__ float pst[16][4][2];
    __shared__ float ls[512];
    cg::grid_group grid = cg::this_grid();
    int b = blockIdx.x;

    prep_phase(a);
    grid.sync();
    if (b < 128) alpha_body(a.zb, a.wsv, a.as1v, a.ad1v, ls);
    grid.sync();
    for (int tile = 0; tile < 2; ++tile)
        aggout_tile((b * 2 + tile) * 16, a.zb, a.eb, a.counts, a.as1v, a.ad1v,
                    a.wr, a.wst1, a.b1, a.lg1, a.lb1, nullptr, a.zb2, sagg, pst);
    grid.sync();
    if (b < 128) alpha_body(a.zb2, a.wsv + 512, a.as2v, a.ad2v, ls);
    grid.sync();
    for (int tile = 0; tile < 2; ++tile)
        aggout_tile((b * 2 + tile) * 16, a.zb2, a.eb, a.counts, a.as2v, a.ad2v,
                    a.wr + 16, a.wst2, a.b2, a.lg2, a.lb2, a.outf, nullptr, sagg, pst);
}

// ---------------- fallback kernels (same device code, 5 launches) -----------
__global__ __launch_bounds__(256) void k_prep(MegaArgs a) { prep_phase(a); }

__global__ __launch_bounds__(256) void k_alpha_fb(const ushort* __restrict__ zsrc,
                                                  const float* __restrict__ wsv,
                                                  float* __restrict__ asv,
                                                  float* __restrict__ adv) {
    __shared__ float ls[512];
    alpha_body(zsrc, wsv, asv, adv, ls);
}

__global__ __launch_bounds__(256, 4) void k_aggout_fb(
        const ushort* __restrict__ zsrc, const uint2* __restrict__ eb,
        const int* __restrict__ counts, const float* __restrict__ asv,
        const float* __restrict__ adv, const float* __restrict__ wrl,
        const ushort* __restrict__ wst, const float* __restrict__ bias,
        const float* __restrict__ lng, const float* __restrict__ lnb,
        float* __restrict__ outf, ushort* __restrict__ outb) {
    __shared__ ushort sagg[16][264];
    __shared__ float pst[16][4][2];
    for (int tile = 0; tile < 2; ++tile)
        aggout_tile((blockIdx.x * 2 + tile) * 16, zsrc, eb, counts, asv, adv,
                    wrl, wst, bias, lng, lnb, outf, outb, sagg, pst);
}

// ---------------- launch ----------------
extern "C" void kernel_launch(void* const* d_in, const int* in_sizes, int n_in,
                              void* d_out, int out_size, void* d_ws, size_t ws_size,
                              hipStream_t stream) {
    const int N = in_sizes[1] / HIDDEN;   // 32768
    const int E = in_sizes[2] / 2;        // 262144

    char* w = (char*)d_ws;
    ushort* zb    = (ushort*)w; w += (size_t)N * HIDDEN * 2;    // 4 MB (z1)
    ushort* zb2   = (ushort*)w; w += (size_t)N * HIDDEN * 2;    // 4 MB (z2)
    float* as1v   = (float*)w;  w += (size_t)N * HEADS * 4;
    float* ad1v   = (float*)w;  w += (size_t)N * HEADS * 4;
    float* as2v   = (float*)w;  w += (size_t)N * HEADS * 4;
    float* ad2v   = (float*)w;  w += (size_t)N * HEADS * 4;
    ushort* wst1  = (ushort*)w; w += 16384 * 2;
    ushort* wst2  = (ushort*)w; w += 16384 * 2;
    float* wsv    = (float*)w;  w += 1024 * 4;
    float* wr     = (float*)w;  w += 128;
    int* counts   = (int*)w;    w += (size_t)N * 4;
    uint2* eb     = (uint2*)w;  w += (size_t)N * CAP * 8;       // 16 MB

    MegaArgs ha;
    ha.dst = (const int*)d_in[2] + E;  ha.src = (const int*)d_in[2];
    ha.ea  = (const float*)d_in[3];    ha.hin = (const float*)d_in[1];
    ha.W1  = (const float*)d_in[4];    ha.W2  = (const float*)d_in[12];
    ha.We1 = (const float*)d_in[5];    ha.ae1 = (const float*)d_in[8];
    ha.We2 = (const float*)d_in[13];   ha.ae2 = (const float*)d_in[16];
    ha.ats1 = (const float*)d_in[6];   ha.atd1 = (const float*)d_in[7];
    ha.ats2 = (const float*)d_in[14];  ha.atd2 = (const float*)d_in[15];
    ha.b1 = (const float*)d_in[9];     ha.lg1 = (const float*)d_in[10];
    ha.lb1 = (const float*)d_in[11];
    ha.b2 = (const float*)d_in[17];    ha.lg2 = (const float*)d_in[18];
    ha.lb2 = (const float*)d_in[19];
    ha.counts = counts; ha.eb = eb; ha.zb = zb; ha.zb2 = zb2;
    ha.wst1 = wst1; ha.wst2 = wst2; ha.wsv = wsv; ha.wr = wr;
    ha.as1v = as1v; ha.ad1v = ad1v; ha.as2v = as2v; ha.ad2v = ad2v;
    ha.outf = (float*)d_out; ha.N = N; ha.E = E;

    hipMemsetAsync(counts, 0, (size_t)N * 4, stream);

    void* kargs[] = { (void*)&ha };
    hipError_t err = hipLaunchCooperativeKernel((const void*)k_mega, dim3(GRID),
                                                dim3(256), kargs, 0, stream);
    if (err != hipSuccess) {
        // fallback: same phases as 5 ordinary kernels
        k_prep<<<GRID, 256, 0, stream>>>(ha);
        k_alpha_fb<<<128, 256, 0, stream>>>(zb, wsv, as1v, ad1v);
        k_aggout_fb<<<GRID, 256, 0, stream>>>(zb, eb, counts, as1v, ad1v, wr,
                                              wst1, ha.b1, ha.lg1, ha.lb1,
                                              nullptr, zb2);
        k_alpha_fb<<<128, 256, 0, stream>>>(zb2, wsv + 512, as2v, ad2v);
        k_aggout_fb<<<GRID, 256, 0, stream>>>(zb2, eb, counts, as2v, ad2v, wr + 16,
                                              wst2, ha.b2, ha.lg2, ha.lb2,
                                              (float*)d_out, nullptr);
    }
}

// Round 6
// 188.356 us; speedup vs baseline: 4.9508x; 4.9508x over previous
//
#include <hip/hip_runtime.h>
#include <math.h>

// Problem constants: N=32768 nodes, E=262144 edges, HID=64, HEADS=4
#define HIDDEN 64
#define HEADS 4
#define HC 256   // HEADS * HIDDEN
#define CAP 64   // bucket capacity per dst node (Poisson(8): P(deg>64) ~ 0)

typedef __attribute__((ext_vector_type(8))) short short8;   // 8 bf16 (4 VGPRs)
typedef __attribute__((ext_vector_type(4))) float f32x4;    // MFMA acc

__device__ __forceinline__ unsigned short f2bf(float f) {
    unsigned int u = __float_as_uint(f);
    u += 0x7fffu + ((u >> 16) & 1u);   // round-to-nearest-even
    return (unsigned short)(u >> 16);
}

__device__ __forceinline__ unsigned short f2h(float f) {
    _Float16 h = (_Float16)f;          // v_cvt_f16_f32, RTN
    return *(unsigned short*)&h;
}

__device__ __forceinline__ float h2f(unsigned int u) {
    unsigned short s = (unsigned short)u;
    _Float16 h = *(_Float16*)&s;
    return (float)h;
}

__device__ __forceinline__ float bflo(unsigned int u) { return __uint_as_float(u << 16); }
__device__ __forceinline__ float bfhi(unsigned int u) { return __uint_as_float(u & 0xffff0000u); }

// ---------------- fused prep + bucket (role-split, no inter-role deps) ------
// [0,1024):     bucket: eb[slot] = {src:u16, a0:f16}{a1:f16, a2:f16}
// [1024,3072):  zb = bf16(h)
// [3072,3200):  wst1/wst2[c*256+k] = bf16(0.25 * W[(k&63)*256 + (k>>6)*64 + c])
// [3200,3204):  wsv[l*512 + type*256 + h*64 + k] = sum_c W_l[k,h*64+c]*att_{s/d}[h,c]
// 3204:         wr (We @ att_edge reductions, both layers)
// Requires counts==0 on entry (hipMemsetAsync before launch).
__global__ __launch_bounds__(256) void k_fused(const int* __restrict__ dst,
                                               const int* __restrict__ src,
                                               const float* __restrict__ ea,
                                               const float* __restrict__ h,
                                               const float* __restrict__ W1f,
                                               const float* __restrict__ W2f,
                                               const float* __restrict__ We1,
                                               const float* __restrict__ ae1,
                                               const float* __restrict__ We2,
                                               const float* __restrict__ ae2,
                                               const float* __restrict__ ats1,
                                               const float* __restrict__ atd1,
                                               const float* __restrict__ ats2,
                                               const float* __restrict__ atd2,
                                               int* __restrict__ counts,
                                               uint2* __restrict__ eb,
                                               ushort* __restrict__ zb,
                                               ushort* __restrict__ wst1,
                                               ushort* __restrict__ wst2,
                                               float* __restrict__ wsv,
                                               float* __restrict__ wr, int E) {
    int t = threadIdx.x, b = blockIdx.x;
    if (b < 1024) {
        int e = b * 256 + t;
        if (e < E) {
            int d = dst[e];
            int c = atomicAdd(&counts[d], 1);
            if (c < CAP) {   // statistically impossible overflow; safety clamp
                size_t slot = (size_t)d * CAP + c;
                unsigned int lo = (unsigned int)(src[e] & 0xffff)
                                | ((unsigned int)f2h(ea[e * 3 + 0]) << 16);
                unsigned int hi = (unsigned int)f2h(ea[e * 3 + 1])
                                | ((unsigned int)f2h(ea[e * 3 + 2]) << 16);
                eb[slot] = make_uint2(lo, hi);
            }
        }
    } else if (b < 3072) {
        int i = (b - 1024) * 256 + t;
        float4 v = ((const float4*)h)[i];
        ushort4 o;
        o.x = f2bf(v.x); o.y = f2bf(v.y); o.z = f2bf(v.z); o.w = f2bf(v.w);
        ((ushort4*)zb)[i] = o;
    } else if (b < 3200) {
        int j = (b - 3072) * 256 + t;        // 0..32767
        const float* W = (j < 16384) ? W1f : W2f;
        ushort* wst = (j < 16384) ? wst1 : wst2;
        int i = j & 16383;
        int c = i >> 8, k = i & 255;
        wst[i] = f2bf(0.25f * W[(k & 63) * HC + (k >> 6) * 64 + c]);
    } else if (b < 3204) {
        int r = b - 3200;                    // layer*2 + type
        const float* W = (r >> 1) ? W2f : W1f;
        const float* at;
        if (r == 0) at = ats1; else if (r == 1) at = atd1;
        else if (r == 2) at = ats2; else at = atd2;
        int hh = t >> 6, k = t & 63;
        const float4* wrow = (const float4*)&W[k * HC + hh * 64];
        const float4* arow = (const float4*)&at[hh * 64];
        float v = 0.f;
#pragma unroll
        for (int c4 = 0; c4 < 16; ++c4) {
            float4 wv = wrow[c4], av = arow[c4];
            v += wv.x * av.x + wv.y * av.y + wv.z * av.z + wv.w * av.w;
        }
        wsv[r * 256 + hh * 64 + k] = v;
    } else {
        int wv = t >> 6, lane = t & 63;
#pragma unroll
        for (int it = 0; it < 6; ++it) {
            int comb = wv + it * 4;          // 0..23
            int layer = comb / 12;
            int dh = comb % 12;
            int d = dh >> 2, hh = dh & 3;
            const float* We = layer ? We2 : We1;
            const float* at = layer ? ae2 : ae1;
            float v = We[d * HC + hh * HIDDEN + lane] * at[hh * HIDDEN + lane];
            for (int o = 32; o > 0; o >>= 1) v += __shfl_down(v, o);
            if (lane == 0) wr[layer * 16 + d * HEADS + hh] = v;
        }
    }
}

// ---------------- layer-1 alpha: as/ad = z @ ws/wd ----------------
__global__ __launch_bounds__(256) void k_alpha(const ushort* __restrict__ zb,
                                               const float* __restrict__ wsv,
                                               float* __restrict__ as_,
                                               float* __restrict__ ad_) {
    __shared__ float ls[512];
    int t = threadIdx.x;
    ls[t] = wsv[t];
    ls[t + 256] = wsv[t + 256];
    __syncthreads();
    int n = blockIdx.x * 256 + t;
    const ushort* zr = zb + (size_t)n * HIDDEN;
    float as[4] = {0.f, 0.f, 0.f, 0.f};
    float ad[4] = {0.f, 0.f, 0.f, 0.f};
#pragma unroll
    for (int ks = 0; ks < 8; ++ks) {
        uint4 v = *(const uint4*)(zr + ks * 8);
        unsigned int uu[4] = {v.x, v.y, v.z, v.w};
#pragma unroll
        for (int p = 0; p < 4; ++p) {
            float f0 = bflo(uu[p]), f1 = bfhi(uu[p]);
            int k = ks * 8 + p * 2;
#pragma unroll
            for (int hh = 0; hh < 4; ++hh) {
                as[hh] += f0 * ls[hh * 64 + k] + f1 * ls[hh * 64 + k + 1];
                ad[hh] += f0 * ls[256 + hh * 64 + k] + f1 * ls[256 + hh * 64 + k + 1];
            }
        }
    }
    *(float4*)&as_[n * 4] = make_float4(as[0], as[1], as[2], as[3]);
    *(float4*)&ad_[n * 4] = make_float4(ad[0], ad[1], ad[2], ad[3]);
}

// ---------------- fused aggregate + out-GEMM (batched alpha chains) ---------
// Block = 256 thr / 4 waves, owns 16 nodes (4 per wave).
// Phase A: 4 independent eb record loads.  Phase B: 4 independent as_ gathers
// + exp (8 scattered loads in flight -> latency MLP x4).  Phase C: per-node
// gather/accumulate with a single reused acc[4][4] (no spill), LDS write.
// Then wave 0 runs the [16,256]@[256,64] MFMA out-GEMM + bias + LN + SiLU.
// Layer 1: writes bf16 z2 + fused as2/ad2. Layer 2: f32 d_out.
__global__ __launch_bounds__(256, 4) void k_aggout(
        const ushort* __restrict__ zb, const uint2* __restrict__ eb,
        const int* __restrict__ counts,
        const float* __restrict__ as_, const float* __restrict__ ad_,
        const float* __restrict__ wrl,
        const ushort* __restrict__ wst, const float* __restrict__ bias,
        const float* __restrict__ lng, const float* __restrict__ lnb,
        const float* __restrict__ wsv2,
        float* __restrict__ as2, float* __restrict__ ad2,
        float* __restrict__ outf, ushort* __restrict__ outb, int N) {
    __shared__ ushort sagg[16][264];   // 16 nodes x 256 ch bf16, +8 pad
    int lane = threadIdx.x & 63;
    int wave = threadIdx.x >> 6;
    int h = lane >> 4, sub = lane & 15;
    int nbase = blockIdx.x * 16;

    float w0 = wrl[h], w1 = wrl[4 + h], w2 = wrl[8 + h];

    int degs[4]; float ad4s[4]; int bases[4];
#pragma unroll
    for (int i = 0; i < 4; ++i) {
        int n = nbase + wave * 4 + i;
        int d = counts[n];
        degs[i] = (d > CAP) ? CAP : d;
        ad4s[i] = ad_[(size_t)n * 4 + h];
        bases[i] = n * CAP;
    }

    // phase A: batched chunk-0 record loads (4 independent)
    uint2 rec[4];
#pragma unroll
    for (int i = 0; i < 4; ++i) rec[i] = eb[bases[i] + sub];

    // phase B: batched as_ gathers + exp (4 independent chains)
    int s_sub[4]; float aq[4];
#pragma unroll
    for (int i = 0; i < 4; ++i)
        s_sub[i] = (sub < degs[i]) ? (int)(rec[i].x & 0xffffu) : 0;
#pragma unroll
    for (int i = 0; i < 4; ++i) aq[i] = as_[(size_t)s_sub[i] * 4 + h];
    float wgt[4];
#pragma unroll
    for (int i = 0; i < 4; ++i) {
        float wv = 0.f;
        if (sub < degs[i]) {
            float lg = aq[i] + ad4s[i]
                     + h2f(rec[i].x >> 16) * w0
                     + h2f(rec[i].y) * w1
                     + h2f(rec[i].y >> 16) * w2;
            lg = (lg >= 0.f) ? lg : 0.2f * lg;
            wv = __expf(lg);
        }
        wgt[i] = wv;
    }

    // phase C: per-node gather + reduce + LDS write (acc reused; no spill)
#pragma unroll 1
    for (int i = 0; i < 4; ++i) {
        int nl = wave * 4 + i;
        int deg = degs[i];
        float ssum = wgt[i];
        float acc[4][4];
#pragma unroll
        for (int a = 0; a < 4; ++a)
#pragma unroll
            for (int j = 0; j < 4; ++j) acc[a][j] = 0.f;

        int m0 = (deg > 16) ? 16 : deg;
        for (int j4 = 0; j4 < m0; j4 += 4) {
            int eidx = j4 + h;                      // edge slot for this lane group
            int s_g = __shfl(s_sub[i], eidx);       // src of edge j4+h (lanes 0-15)
            uint2 zv = *(const uint2*)&zb[(size_t)s_g * HIDDEN + sub * 4];
            float z0 = bflo(zv.x), z1 = bfhi(zv.x);
            float z2v = bflo(zv.y), z3 = bfhi(zv.y);
#pragma unroll
            for (int hh = 0; hh < 4; ++hh) {
                float wh = __shfl(wgt[i], hh * 16 + eidx);   // 0 past deg
                acc[hh][0] += wh * z0;
                acc[hh][1] += wh * z1;
                acc[hh][2] += wh * z2v;
                acc[hh][3] += wh * z3;
            }
        }

        // tail chunks (deg > 16, ~0.4% of nodes): recompute weights per chunk
        for (int cs = 16; cs < deg; cs += 16) {
            int idx = cs + sub;
            int st = 0; float wt = 0.f;
            if (idx < deg) {
                uint2 rt = eb[bases[i] + idx];
                st = (int)(rt.x & 0xffffu);
                float lg = as_[(size_t)st * 4 + h] + ad4s[i]
                         + h2f(rt.x >> 16) * w0 + h2f(rt.y) * w1
                         + h2f(rt.y >> 16) * w2;
                lg = (lg >= 0.f) ? lg : 0.2f * lg;
                wt = __expf(lg);
            }
            ssum += wt;
            int jb = deg - cs; if (jb > 16) jb = 16;
            for (int j4 = 0; j4 < jb; j4 += 4) {
                int eidx = j4 + h;
                int s_g = __shfl(st, eidx);
                uint2 zv = *(const uint2*)&zb[(size_t)s_g * HIDDEN + sub * 4];
                float z0 = bflo(zv.x), z1 = bfhi(zv.x);
                float z2v = bflo(zv.y), z3 = bfhi(zv.y);
#pragma unroll
                for (int hh = 0; hh < 4; ++hh) {
                    float wh = __shfl(wt, hh * 16 + eidx);
                    acc[hh][0] += wh * z0;
                    acc[hh][1] += wh * z1;
                    acc[hh][2] += wh * z2v;
                    acc[hh][3] += wh * z3;
                }
            }
        }

        // softmax denom per head (reduce over bits 0..3 of lane)
#pragma unroll
        for (int o = 1; o < 16; o <<= 1) ssum += __shfl_xor(ssum, o);
        float winv = 1.f / (ssum + 1e-16f);
        // reduce acc over edge-slot groups (bits 4,5)
#pragma unroll
        for (int a = 0; a < 4; ++a)
#pragma unroll
            for (int j = 0; j < 4; ++j) {
                acc[a][j] += __shfl_xor(acc[a][j], 16);
                acc[a][j] += __shfl_xor(acc[a][j], 32);
            }
        // lane (h, sub) writes head h, channels sub*4..+3 (static-index select)
        float sel[4];
#pragma unroll
        for (int j = 0; j < 4; ++j)
            sel[j] = (h == 0) ? acc[0][j] : (h == 1) ? acc[1][j]
                   : (h == 2) ? acc[2][j] : acc[3][j];
        uint2 pk;
        pk.x = (unsigned)f2bf(sel[0] * winv) | ((unsigned)f2bf(sel[1] * winv) << 16);
        pk.y = (unsigned)f2bf(sel[2] * winv) | ((unsigned)f2bf(sel[3] * winv) << 16);
        *(uint2*)&sagg[nl][h * 64 + sub * 4] = pk;
    }
    __syncthreads();

    if (wave == 0) {
        int q = lane & 15, quad = lane >> 4;
        short8 a[8];
#pragma unroll
        for (int ks = 0; ks < 8; ++ks)
            a[ks] = *(const short8*)&sagg[q][quad * 8 + ks * 32];

        f32x4 acc[4];
#pragma unroll
        for (int nt = 0; nt < 4; ++nt) {
            const ushort* brow = wst + (size_t)(nt * 16 + q) * HC + quad * 8;
            f32x4 c4 = {0.f, 0.f, 0.f, 0.f};
#pragma unroll
            for (int ks = 0; ks < 8; ++ks) {
                short8 bfr = *(const short8*)(brow + ks * 32);
                c4 = __builtin_amdgcn_mfma_f32_16x16x32_bf16(a[ks], bfr, c4, 0, 0, 0);
            }
            acc[nt] = c4;
        }

        // epilogue: bias (0.25 head-mean folded into wst) + LN + SiLU
        float u[4][4], s1[4] = {0.f, 0.f, 0.f, 0.f};
#pragma unroll
        for (int nt = 0; nt < 4; ++nt) {
            float bv = bias[nt * 16 + q];
#pragma unroll
            for (int r = 0; r < 4; ++r) { u[nt][r] = acc[nt][r] + bv; s1[r] += u[nt][r]; }
        }
#pragma unroll
        for (int o = 1; o < 16; o <<= 1)
#pragma unroll
            for (int r = 0; r < 4; ++r) s1[r] += __shfl_xor(s1[r], o);
        float mu[4], s2[4] = {0.f, 0.f, 0.f, 0.f};
#pragma unroll
        for (int r = 0; r < 4; ++r) mu[r] = s1[r] * (1.f / 64.f);
#pragma unroll
        for (int nt = 0; nt < 4; ++nt)
#pragma unroll
            for (int r = 0; r < 4; ++r) { float d = u[nt][r] - mu[r]; s2[r] += d * d; }
#pragma unroll
        for (int o = 1; o < 16; o <<= 1)
#pragma unroll
            for (int r = 0; r < 4; ++r) s2[r] += __shfl_xor(s2[r], o);
        float rstd[4];
#pragma unroll
        for (int r = 0; r < 4; ++r) rstd[r] = rsqrtf(s2[r] * (1.f / 64.f) + 1e-5f);

        float rv[4][4];
#pragma unroll
        for (int nt = 0; nt < 4; ++nt) {
            float gv = lng[nt * 16 + q], bb = lnb[nt * 16 + q];
#pragma unroll
            for (int r = 0; r < 4; ++r) {
                float y = (u[nt][r] - mu[r]) * rstd[r] * gv + bb;
                rv[nt][r] = y / (1.f + __expf(-y));
            }
        }

        if (outb) {
#pragma unroll
            for (int nt = 0; nt < 4; ++nt)
#pragma unroll
                for (int r = 0; r < 4; ++r)
                    outb[(size_t)(nbase + quad * 4 + r) * HIDDEN + nt * 16 + q] = f2bf(rv[nt][r]);
            // fused next-layer alpha: as2/ad2 = z2 @ ws2/wd2
            float vs[4][4] = {{0.f}}, vd[4][4] = {{0.f}};
#pragma unroll
            for (int hh = 0; hh < 4; ++hh)
#pragma unroll
                for (int nt = 0; nt < 4; ++nt) {
                    float wsc = wsv2[hh * 64 + nt * 16 + q];
                    float wdc = wsv2[256 + hh * 64 + nt * 16 + q];
#pragma unroll
                    for (int r = 0; r < 4; ++r) {
                        vs[r][hh] += rv[nt][r] * wsc;
                        vd[r][hh] += rv[nt][r] * wdc;
                    }
                }
#pragma unroll
            for (int o = 1; o < 16; o <<= 1)
#pragma unroll
                for (int r = 0; r < 4; ++r)
#pragma unroll
                    for (int hh = 0; hh < 4; ++hh) {
                        vs[r][hh] += __shfl_xor(vs[r][hh], o);
                        vd[r][hh] += __shfl_xor(vd[r][hh], o);
                    }
            if (q < 4) {
#pragma unroll
                for (int r = 0; r < 4; ++r) {
                    float sv = (q == 0) ? vs[r][0] : (q == 1) ? vs[r][1]
                             : (q == 2) ? vs[r][2] : vs[r][3];
                    float dv = (q == 0) ? vd[r][0] : (q == 1) ? vd[r][1]
                             : (q == 2) ? vd[r][2] : vd[r][3];
                    int n = nbase + quad * 4 + r;
                    as2[(size_t)n * 4 + q] = sv;
                    ad2[(size_t)n * 4 + q] = dv;
                }
            }
        } else {
#pragma unroll
            for (int nt = 0; nt < 4; ++nt)
#pragma unroll
                for (int r = 0; r < 4; ++r)
                    outf[(size_t)(nbase + quad * 4 + r) * HIDDEN + nt * 16 + q] = rv[nt][r];
        }
    }
}

// ---------------- launch ----------------

extern "C" void kernel_launch(void* const* d_in, const int* in_sizes, int n_in,
                              void* d_out, int out_size, void* d_ws, size_t ws_size,
                              hipStream_t stream) {
    const float* h   = (const float*)d_in[1];
    const int*   ei  = (const int*)d_in[2];
    const float* ea  = (const float*)d_in[3];
    const float* W1  = (const float*)d_in[4];
    const float* We1 = (const float*)d_in[5];
    const float* as1 = (const float*)d_in[6];
    const float* ad1 = (const float*)d_in[7];
    const float* ae1 = (const float*)d_in[8];
    const float* b1  = (const float*)d_in[9];
    const float* lg1 = (const float*)d_in[10];
    const float* lb1 = (const float*)d_in[11];
    const float* W2  = (const float*)d_in[12];
    const float* We2 = (const float*)d_in[13];
    const float* as2 = (const float*)d_in[14];
    const float* ad2 = (const float*)d_in[15];
    const float* ae2 = (const float*)d_in[16];
    const float* b2  = (const float*)d_in[17];
    const float* lg2 = (const float*)d_in[18];
    const float* lb2 = (const float*)d_in[19];

    const int N = in_sizes[1] / HIDDEN;   // 32768
    const int E = in_sizes[2] / 2;        // 262144
    const int* srcp = ei;
    const int* dstp = ei + E;

    // workspace layout (all regions fully written before read)
    char* w = (char*)d_ws;
    ushort* zb    = (ushort*)w; w += (size_t)N * HIDDEN * 2;    // 4 MB  (z1)
    ushort* zb2   = (ushort*)w; w += (size_t)N * HIDDEN * 2;    // 4 MB  (z2)
    float* as_    = (float*)w;  w += (size_t)N * HEADS * 4;
    float* adv    = (float*)w;  w += (size_t)N * HEADS * 4;
    float* as2_   = (float*)w;  w += (size_t)N * HEADS * 4;
    float* ad2_   = (float*)w;  w += (size_t)N * HEADS * 4;
    ushort* wst1  = (ushort*)w; w += 16384 * 2;
    ushort* wst2  = (ushort*)w; w += 16384 * 2;
    float* wsv    = (float*)w;  w += 1024 * 4;                  // [2][2][4][64]
    float* wr     = (float*)w;  w += 128;
    int* counts   = (int*)w;    w += (size_t)N * 4;
    uint2* eb     = (uint2*)w;  w += (size_t)N * CAP * 8;       // 16 MB packed records

    // zero counts, then fused prep || bucket
    hipMemsetAsync(counts, 0, (size_t)N * 4, stream);
    k_fused<<<3205, 256, 0, stream>>>(dstp, srcp, ea, h, W1, W2,
                                      We1, ae1, We2, ae2,
                                      as1, ad1, as2, ad2,
                                      counts, eb, zb, wst1, wst2, wsv, wr, E);

    k_alpha<<<N / 256, 256, 0, stream>>>(zb, wsv, as_, adv);

    // layer 1: aggregate z1 + out-GEMM -> z2 (bf16) + as2/ad2
    k_aggout<<<N / 16, 256, 0, stream>>>(zb, eb, counts, as_, adv, wr,
                                         wst1, b1, lg1, lb1, wsv + 512,
                                         as2_, ad2_, nullptr, zb2, N);
    // layer 2: aggregate z2 + out-GEMM -> d_out (f32)
    k_aggout<<<N / 16, 256, 0, stream>>>(zb2, eb, counts, as2_, ad2_, wr + 16,
                                         wst2, b2, lg2, lb2, nullptr,
                                         nullptr, nullptr, (float*)d_out, nullptr, N);
}